// Round 3
// baseline (660.531 us; speedup 1.0000x reference)
//
#include <hip/hip_runtime.h>

// Problem constants: B=8, flow (B,2,H,W), depth (B,1,H,W), fp32.
constexpr int B  = 8;
constexpr int H  = 720;
constexpr int W  = 1280;
constexpr int HW = H * W;           // 921600
constexpr int N  = B * HW;          // 7372800

// Gather geometry. Inlier band: fx,fy in [-3,3). An inlier source can only
// touch outputs within Chebyshev distance 3. Gather blocks own 64x48 output
// tiles and scan tile+halo sources.
//
// BIT-EXACT match test (round-2 lesson): the reference floors x2 = fl(gx+fx)
// computed in fp32. Testing fx+dx ranges is NOT equivalent (fl(gx+fx) can
// round across an integer at half-ulp ~6e-5; ~10^3 of 7.4M sources flip ->
// absmax ~2.8 FAIL). So we stage the ABSOLUTE fp32 targets (x2, y2) and test
//   column match: x2 in [oxa-1, oxa+1)   (floor(x2) == oxa-1 or oxa)
//   row r match:  y2 in [oyb+r-1, oyb+r+1)
// against exact integer-valued float boundaries — bit-identical to floor.
// Numerators -fx*w, -fy*w are recovered as (gx - x2)*w, (gy - y2)*w
// (error <= ulp/2 ~6e-5 per splat, threshold is 9.4e-2).
// Clamp-edge cases (x2==W-1 or y2==H-1 exactly) go to the outlier pass.
constexpr int TX = 64;              // tile cols  (1280/64 = 20)
constexpr int TY = 48;              // tile rows  (720/48  = 15)
constexpr int C  = 3;
constexpr int RW = TX + 2 * C;      // 70 staged cols
constexpr int RH = TY + 2 * C;      // 54 staged rows
constexpr int RN = RW * RH;         // 3780 staged sources (60480 B as float4)
constexpr int PY = 4;               // output rows per thread per pass
// 256 threads = 64 cols x 4 row-groups; 3 passes cover 48 rows.

// ---------------------------------------------------------------------------
// Outlier pass: valid sources NOT handled by the gather fast path, i.e.
// outside the [-3,3) band OR exact clamp hits (x2==W-1 / y2==H-1). Exact
// global atomics into zeroed ws planes. Vectorized 4 px/thread; the atomic
// cluster is skipped by execz when no lane has an outlier.
// ---------------------------------------------------------------------------
__global__ __launch_bounds__(256) void dfp_outlier(
    const float* __restrict__ flow, const float* __restrict__ depth,
    float* __restrict__ pcnt, float* __restrict__ pox, float* __restrict__ poy)
{
    int t = blockIdx.x * 256 + threadIdx.x;
    if (t >= N / 4) return;
    int t4 = t * 4;
    int b  = t4 / HW;
    int p  = t4 - b * HW;
    int i  = p / W;
    int j  = p - i * W;                       // multiple of 4 (W%4==0)

    const float* fxp = flow + b * 2 * HW;
    float4 fx4 = *(const float4*)(fxp + p);
    float4 fy4 = *(const float4*)(fxp + HW + p);
    float fxs[4] = {fx4.x, fx4.y, fx4.z, fx4.w};
    float fys[4] = {fy4.x, fy4.y, fy4.z, fy4.w};

    float* cb = pcnt + b * HW;
    float* xb = pox  + b * HW;
    float* yb = poy  + b * HW;

    #pragma unroll
    for (int e = 0; e < 4; ++e) {
        float fx = fxs[e], fy = fys[e];
        float x2 = (float)(j + e) + fx;
        float y2 = (float)i + fy;
        bool valid = (x2 >= 0.0f) && (x2 <= (float)(W - 1)) &&
                     (y2 >= 0.0f) && (y2 <= (float)(H - 1));
        bool band  = (fx >= -3.0f) && (fx < 3.0f) &&
                     (fy >= -3.0f) && (fy < 3.0f);
        // Gather fast path handles: band && x2<W-1 && y2<H-1 (given valid).
        // MUST match dfp_gather's staging predicate exactly.
        bool fast  = band && (x2 < (float)(W - 1)) && (y2 < (float)(H - 1));
        if (valid && !fast) {
            float d  = depth[t4 + e];
            int xL = (int)floorf(x2);
            int yT = (int)floorf(y2);
            int xR = min(xL + 1, W - 1);
            int yB = min(yT + 1, H - 1);
            float w = d, gx = -fx * d, gy = -fy * d;
            int n00 = yT * W + xL, n01 = yT * W + xR;
            int n10 = yB * W + xL, n11 = yB * W + xR;
            unsafeAtomicAdd(&cb[n00], w); unsafeAtomicAdd(&xb[n00], gx); unsafeAtomicAdd(&yb[n00], gy);
            unsafeAtomicAdd(&cb[n01], w); unsafeAtomicAdd(&xb[n01], gx); unsafeAtomicAdd(&yb[n01], gy);
            unsafeAtomicAdd(&cb[n10], w); unsafeAtomicAdd(&xb[n10], gx); unsafeAtomicAdd(&yb[n10], gy);
            unsafeAtomicAdd(&cb[n11], w); unsafeAtomicAdd(&xb[n11], gx); unsafeAtomicAdd(&yb[n11], gy);
        }
    }
}

// ---------------------------------------------------------------------------
// Gather kernel v3: NO atomics, NO floor/int math in the inner loop, and
// bit-exact attribution. Stage (x2, y2, w, 0) float4 per source (w=0 for
// dead sources; x2=y2=0 there so masked-zero FMAs can't make NaN).
// Inner loop per candidate: 1 ds_read_b128, 8 v_cmp vs exact integer floats,
// 2 v_sub (recover -fx*?, -fy*?), 4 cndmask, 4 add, 8 fma.
// ---------------------------------------------------------------------------
__global__ __launch_bounds__(256) void dfp_gather(
    const float* __restrict__ flow, const float* __restrict__ depth,
    const float* __restrict__ pcnt, const float* __restrict__ pox,
    const float* __restrict__ poy, float* __restrict__ out)
{
    __shared__ float4 sq[RN];        // (x2, y2, w, pad)  60480 B

    const int tid = threadIdx.x;
    const int tx0 = blockIdx.x * TX;
    const int ty0 = blockIdx.y * TY;
    const int b   = blockIdx.z;

    const float* fxp = flow + b * 2 * HW;
    const float* fyp = fxp + HW;
    const float* dp  = depth + b * HW;

    // ---- Stage tile + halo. w=0 encodes "no contribution here".
    for (int k = tid; k < RN; k += 256) {
        int ry = k / RW;                 // const divisor -> magic mul
        int rx = k - ry * RW;
        int gy = ty0 - C + ry;
        int gx = tx0 - C + rx;
        float X = 0.f, Y = 0.f, w = 0.f;
        if ((unsigned)gy < (unsigned)H && (unsigned)gx < (unsigned)W) {
            int g = gy * W + gx;
            float fx = fxp[g];
            float fy = fyp[g];
            float x2 = (float)gx + fx;   // EXACTLY the reference's fp32 x2
            float y2 = (float)gy + fy;
            // band && valid && not-clamp-edge.
            // MUST match dfp_outlier's complement exactly.
            if (fx >= -3.0f && fx < 3.0f && fy >= -3.0f && fy < 3.0f &&
                x2 >= 0.0f && x2 < (float)(W - 1) &&
                y2 >= 0.0f && y2 < (float)(H - 1)) {
                X = x2; Y = y2; w = dp[g];
            }
        }
        sq[k] = make_float4(X, Y, w, 0.f);
    }
    __syncthreads();

    const int ox  = tid & 63;            // tile-local column (0..63)
    const int g0  = tid >> 6;            // row group (0..3)
    const int oxa = tx0 + ox;            // absolute output column

    const float oxaF = (float)oxa;
    const float cLo  = oxaF - 1.0f;      // exact integers as floats
    const float cHi  = oxaF + 1.0f;

    float* outx = out + b * 2 * HW;
    float* outy = outx + HW;
    const float* cb = pcnt + b * HW;
    const float* xb = pox  + b * HW;
    const float* yb = poy  + b * HW;

    for (int pass = 0; pass < 3; ++pass) {
        const int oy0 = pass * 16 + g0 * PY;   // tile-local first owned row
        const int oyb = ty0 + oy0;             // absolute row of r=0
        const float oybF = (float)oyb;
        // Row boundaries (exact integer floats): t_k = (y2 >= oyb+k).
        const float bm1 = oybF - 1.0f;
        const float b0  = oybF;
        const float b1  = oybF + 1.0f;
        const float b2  = oybF + 2.0f;
        const float b3  = oybF + 3.0f;
        const float b4  = oybF + 4.0f;

        float c0 = 0.f, c1 = 0.f, c2 = 0.f, c3 = 0.f;
        float x0 = 0.f, x1 = 0.f, x2a = 0.f, x3 = 0.f;
        float y0 = 0.f, y1 = 0.f, y2a = 0.f, y3 = 0.f;

        #pragma unroll
        for (int dy = -C; dy <= PY - 1 + C; ++dy) {      // 10 rows
            const int   base = (oy0 + dy + C) * RW + ox; // + (dx+C)
            const float gyF  = oybF + (float)dy;         // exact source row
            #pragma unroll
            for (int dx = -C; dx <= C; ++dx) {           // 7 cols
                float4 f = sq[base + dx + C];
                const float X = f.x, Y = f.y, w = f.z;
                // Column: floor(X) in {oxa-1, oxa}  <=>  X in [oxa-1, oxa+1)
                bool cx  = (X >= cLo) & (X < cHi);
                bool tm1 = (Y >= bm1);
                bool t1  = (Y >= b1);
                bool t0  = (Y >= b0);
                bool t2  = (Y >= b2);
                bool t3  = (Y >= b3);
                bool t4  = (Y >= b4);
                bool m0 = cx & tm1 & !t1;    // Y in [oyb-1, oyb+1)
                bool m1 = cx & t0  & !t2;    // Y in [oyb+0, oyb+2)
                bool m2 = cx & t1  & !t3;    // Y in [oyb+1, oyb+3)
                bool m3 = cx & t2  & !t4;    // Y in [oyb+2, oyb+4)

                float ax = (oxaF + (float)dx) - X;   // == -(fx + eps)
                float ay = gyF - Y;                  // == -(fy + eps)

                float w0 = m0 ? w : 0.0f;
                float w1 = m1 ? w : 0.0f;
                float w2 = m2 ? w : 0.0f;
                float w3 = m3 ? w : 0.0f;
                c0 += w0;  x0  = fmaf(ax, w0, x0 );  y0  = fmaf(ay, w0, y0 );
                c1 += w1;  x1  = fmaf(ax, w1, x1 );  y1  = fmaf(ay, w1, y1 );
                c2 += w2;  x2a = fmaf(ax, w2, x2a);  y2a = fmaf(ay, w2, y2a);
                c3 += w3;  x3  = fmaf(ax, w3, x3 );  y3  = fmaf(ay, w3, y3 );
            }
        }

        // ---- Flush: add outlier planes, normalize, write. Coalesced (lane=ox).
        float cc[PY] = {c0, c1, c2, c3};
        float vx[PY] = {x0, x1, x2a, x3};
        float vy[PY] = {y0, y1, y2a, y3};
        #pragma unroll
        for (int r = 0; r < PY; ++r) {
            int ga = (oyb + r) * W + oxa;
            float c  = cc[r] + cb[ga];
            float fx = vx[r] + xb[ga];
            float fy = vy[r] + yb[ga];
            bool has = c > 0.0f;
            outx[ga] = has ? fx / c : 0.0f;
            outy[ga] = has ? fy / c : 0.0f;
        }
    }
}

// ---------------------------------------------------------------------------
// Fallback path (Round-2 proven): used only if ws can't hold 3 planes.
// ---------------------------------------------------------------------------
__global__ __launch_bounds__(256) void dfp_scatter(
    const float* __restrict__ flow, const float* __restrict__ depth,
    float* __restrict__ out, float* __restrict__ count)
{
    int t = blockIdx.x * 256 + threadIdx.x;
    if (t >= N) return;
    int b = t / HW;
    int p = t - b * HW;
    int i = p / W;
    int j = p - i * W;
    const int fbase = b * 2 * HW;
    float fx = flow[fbase + p];
    float fy = flow[fbase + HW + p];
    float d  = depth[t];
    float x2 = (float)j + fx;
    float y2 = (float)i + fy;
    if (!(x2 >= 0.0f && x2 <= (float)(W - 1) &&
          y2 >= 0.0f && y2 <= (float)(H - 1))) return;
    int xL = (int)floorf(x2);
    int yT = (int)floorf(y2);
    int xR = min(xL + 1, W - 1);
    int yB = min(yT + 1, H - 1);
    float w = d, gx = -fx * w, gy = -fy * w;
    float* ox = out + fbase;
    float* oy = out + fbase + HW;
    float* cnt = count + b * HW;
    int n00 = yT * W + xL, n01 = yT * W + xR, n10 = yB * W + xL, n11 = yB * W + xR;
    unsafeAtomicAdd(&cnt[n00], w); unsafeAtomicAdd(&ox[n00], gx); unsafeAtomicAdd(&oy[n00], gy);
    unsafeAtomicAdd(&cnt[n01], w); unsafeAtomicAdd(&ox[n01], gx); unsafeAtomicAdd(&oy[n01], gy);
    unsafeAtomicAdd(&cnt[n10], w); unsafeAtomicAdd(&ox[n10], gx); unsafeAtomicAdd(&oy[n10], gy);
    unsafeAtomicAdd(&cnt[n11], w); unsafeAtomicAdd(&ox[n11], gx); unsafeAtomicAdd(&oy[n11], gy);
}

__global__ __launch_bounds__(256) void dfp_normalize(
    float* __restrict__ out, const float* __restrict__ count)
{
    int t = blockIdx.x * 256 + threadIdx.x;
    if (t >= N / 4) return;
    int t4 = t * 4;
    int b  = t4 / HW;
    int p  = t4 - b * HW;
    float4 c = *(const float4*)(count + t4);
    float* ox = out + b * 2 * HW + p;
    float* oy = ox + HW;
    float4 vx = *(const float4*)ox;
    float4 vy = *(const float4*)oy;
    vx.x = (c.x > 0.0f) ? vx.x / c.x : 0.0f;
    vx.y = (c.y > 0.0f) ? vx.y / c.y : 0.0f;
    vx.z = (c.z > 0.0f) ? vx.z / c.z : 0.0f;
    vx.w = (c.w > 0.0f) ? vx.w / c.w : 0.0f;
    vy.x = (c.x > 0.0f) ? vy.x / c.x : 0.0f;
    vy.y = (c.y > 0.0f) ? vy.y / c.y : 0.0f;
    vy.z = (c.z > 0.0f) ? vy.z / c.z : 0.0f;
    vy.w = (c.w > 0.0f) ? vy.w / c.w : 0.0f;
    *(float4*)ox = vx;
    *(float4*)oy = vy;
}

extern "C" void kernel_launch(void* const* d_in, const int* in_sizes, int n_in,
                              void* d_out, int out_size, void* d_ws, size_t ws_size,
                              hipStream_t stream)
{
    const float* flow  = (const float*)d_in[0];
    const float* depth = (const float*)d_in[1];
    float* out = (float*)d_out;

    if (ws_size >= (size_t)3 * N * sizeof(float)) {
        // Fast path: bit-exact absolute-coordinate gather + exact outlier pass.
        float* pcnt = (float*)d_ws;
        float* pox  = pcnt + N;
        float* poy  = pox + N;
        hipMemsetAsync(pcnt, 0, (size_t)3 * N * sizeof(float), stream);
        dfp_outlier<<<(N / 4 + 255) / 256, 256, 0, stream>>>(flow, depth, pcnt, pox, poy);
        dim3 grid(W / TX, H / TY, B);   // 20 x 15 x 8 = 2400 blocks
        dfp_gather<<<grid, 256, 0, stream>>>(flow, depth, pcnt, pox, poy, out);
    } else if (ws_size >= (size_t)N * sizeof(float)) {
        // Fallback: proven Round-2 global-atomic path.
        float* count = (float*)d_ws;
        hipMemsetAsync(out,   0, (size_t)2 * N * sizeof(float), stream);
        hipMemsetAsync(count, 0, (size_t)N * sizeof(float),     stream);
        dfp_scatter  <<<(N + 255) / 256,     256, 0, stream>>>(flow, depth, out, count);
        dfp_normalize<<<(N / 4 + 255) / 256, 256, 0, stream>>>(out, count);
    }
    // else: insufficient workspace — cannot run safely.
}

// Round 4
// 310.782 us; speedup vs baseline: 2.1254x; 2.1254x over previous
//
#include <hip/hip_runtime.h>

// Problem constants: B=8, flow (B,2,H,W), depth (B,1,H,W), fp32.
constexpr int B  = 8;
constexpr int H  = 720;
constexpr int W  = 1280;
constexpr int HW = H * W;           // 921600
constexpr int N  = B * HW;          // 7372800

// Gather geometry. Inlier band: fx,fy in [-3,3). An inlier source can only
// touch outputs within Chebyshev distance 3. Gather blocks own 64x48 output
// tiles and scan tile+halo sources.
//
// BIT-EXACT match test (round-2 lesson): the reference floors x2 = fl(gx+fx)
// computed in fp32. We stage the ABSOLUTE fp32 targets (x2, y2) and test
//   column match: x2 in [oxa-1, oxa+1)   (floor(x2) == oxa-1 or oxa)
//   row r match:  y2 in [oyb+r-1, oyb+r+1)
// against exact integer-valued float boundaries — bit-identical to floor.
// Numerators -fx*w, -fy*w are recovered as (gx - x2)*w, (gy - y2)*w
// (error <= ulp/2 ~6e-5 per splat; threshold 9.4e-2; round-3 absmax 0.016 OK).
// Clamp-edge cases (x2==W-1 or y2==H-1 exactly) go to the outlier pass.
//
// ROUND-3 LESSON: do NOT unroll the dy loop. Full 70-candidate unroll hoisted
// all ds_reads -> 236 VGPR -> 11% occupancy -> latency-bound 539 us. Round-0
// shape (rolled dy, float2+float staging, 68 VGPR, 3 blocks/CU) + this
// 26-inst inner body is the target: ~43 us VALU + ~46 us DS overlapped.
constexpr int TX = 64;              // tile cols  (1280/64 = 20)
constexpr int TY = 48;              // tile rows  (720/48  = 15)
constexpr int C  = 3;
constexpr int RW = TX + 2 * C;      // 70 staged cols
constexpr int RH = TY + 2 * C;      // 54 staged rows
constexpr int RN = RW * RH;         // 3780 staged sources
constexpr int PY = 4;               // output rows per thread per pass
// 256 threads = 64 cols x 4 row-groups; 3 passes cover 48 rows.

// ---------------------------------------------------------------------------
// Outlier pass: valid sources NOT handled by the gather fast path, i.e.
// outside the [-3,3) band OR exact clamp hits (x2==W-1 / y2==H-1). Exact
// global atomics into zeroed ws planes. Vectorized 4 px/thread.
// ---------------------------------------------------------------------------
__global__ __launch_bounds__(256) void dfp_outlier(
    const float* __restrict__ flow, const float* __restrict__ depth,
    float* __restrict__ pcnt, float* __restrict__ pox, float* __restrict__ poy)
{
    int t = blockIdx.x * 256 + threadIdx.x;
    if (t >= N / 4) return;
    int t4 = t * 4;
    int b  = t4 / HW;
    int p  = t4 - b * HW;
    int i  = p / W;
    int j  = p - i * W;                       // multiple of 4 (W%4==0)

    const float* fxp = flow + b * 2 * HW;
    float4 fx4 = *(const float4*)(fxp + p);
    float4 fy4 = *(const float4*)(fxp + HW + p);
    float fxs[4] = {fx4.x, fx4.y, fx4.z, fx4.w};
    float fys[4] = {fy4.x, fy4.y, fy4.z, fy4.w};

    float* cb = pcnt + b * HW;
    float* xb = pox  + b * HW;
    float* yb = poy  + b * HW;

    #pragma unroll
    for (int e = 0; e < 4; ++e) {
        float fx = fxs[e], fy = fys[e];
        float x2 = (float)(j + e) + fx;
        float y2 = (float)i + fy;
        bool valid = (x2 >= 0.0f) && (x2 <= (float)(W - 1)) &&
                     (y2 >= 0.0f) && (y2 <= (float)(H - 1));
        bool band  = (fx >= -3.0f) && (fx < 3.0f) &&
                     (fy >= -3.0f) && (fy < 3.0f);
        // Gather fast path handles: band && x2<W-1 && y2<H-1 (given valid).
        // MUST match dfp_gather's staging predicate exactly.
        bool fast  = band && (x2 < (float)(W - 1)) && (y2 < (float)(H - 1));
        if (valid && !fast) {
            float d  = depth[t4 + e];
            int xL = (int)floorf(x2);
            int yT = (int)floorf(y2);
            int xR = min(xL + 1, W - 1);
            int yB = min(yT + 1, H - 1);
            float w = d, gx = -fx * d, gy = -fy * d;
            int n00 = yT * W + xL, n01 = yT * W + xR;
            int n10 = yB * W + xL, n11 = yB * W + xR;
            unsafeAtomicAdd(&cb[n00], w); unsafeAtomicAdd(&xb[n00], gx); unsafeAtomicAdd(&yb[n00], gy);
            unsafeAtomicAdd(&cb[n01], w); unsafeAtomicAdd(&xb[n01], gx); unsafeAtomicAdd(&yb[n01], gy);
            unsafeAtomicAdd(&cb[n10], w); unsafeAtomicAdd(&xb[n10], gx); unsafeAtomicAdd(&yb[n10], gy);
            unsafeAtomicAdd(&cb[n11], w); unsafeAtomicAdd(&xb[n11], gx); unsafeAtomicAdd(&yb[n11], gy);
        }
    }
}

// ---------------------------------------------------------------------------
// Gather kernel v4: round-0 execution shape (rolled dy, float2+float staging,
// 3 blocks/CU) + round-3 bit-exact 26-inst inner body. No atomics, no floor
// in the inner loop. Stage (x2, y2) float2 + w float (w=0 for dead sources;
// x2=y2=0 there so masked-zero FMAs can't make NaN).
// ---------------------------------------------------------------------------
__global__ __launch_bounds__(256) void dfp_gather(
    const float* __restrict__ flow, const float* __restrict__ depth,
    const float* __restrict__ pcnt, const float* __restrict__ pox,
    const float* __restrict__ poy, float* __restrict__ out)
{
    __shared__ float2 sxy[RN];       // (x2, y2)  30240 B
    __shared__ float  sw [RN];       // w         15120 B   (total 45360 B)

    const int tid = threadIdx.x;
    const int tx0 = blockIdx.x * TX;
    const int ty0 = blockIdx.y * TY;
    const int b   = blockIdx.z;

    const float* fxp = flow + b * 2 * HW;
    const float* fyp = fxp + HW;
    const float* dp  = depth + b * HW;

    // ---- Stage tile + halo. w=0 encodes "no contribution here".
    for (int k = tid; k < RN; k += 256) {
        int ry = k / RW;                 // const divisor -> magic mul
        int rx = k - ry * RW;
        int gy = ty0 - C + ry;
        int gx = tx0 - C + rx;
        float X = 0.f, Y = 0.f, w = 0.f;
        if ((unsigned)gy < (unsigned)H && (unsigned)gx < (unsigned)W) {
            int g = gy * W + gx;
            float fx = fxp[g];
            float fy = fyp[g];
            float x2 = (float)gx + fx;   // EXACTLY the reference's fp32 x2
            float y2 = (float)gy + fy;
            // band && valid && not-clamp-edge.
            // MUST match dfp_outlier's complement exactly.
            if (fx >= -3.0f && fx < 3.0f && fy >= -3.0f && fy < 3.0f &&
                x2 >= 0.0f && x2 < (float)(W - 1) &&
                y2 >= 0.0f && y2 < (float)(H - 1)) {
                X = x2; Y = y2; w = dp[g];
            }
        }
        sxy[k] = make_float2(X, Y);
        sw [k] = w;
    }
    __syncthreads();

    const int ox  = tid & 63;            // tile-local column (0..63)
    const int g0  = tid >> 6;            // row group (0..3)
    const int oxa = tx0 + ox;            // absolute output column

    const float oxaF = (float)oxa;
    const float cLo  = oxaF - 1.0f;      // exact integers as floats
    const float cHi  = oxaF + 1.0f;

    float* outx = out + b * 2 * HW;
    float* outy = outx + HW;
    const float* cb = pcnt + b * HW;
    const float* xb = pox  + b * HW;
    const float* yb = poy  + b * HW;

    for (int pass = 0; pass < 3; ++pass) {
        const int oy0 = pass * 16 + g0 * PY;   // tile-local first owned row
        const int oyb = ty0 + oy0;             // absolute row of r=0
        const float oybF = (float)oyb;
        // Row boundaries (exact integer floats): t_k = (y2 >= oyb+k).
        const float bm1 = oybF - 1.0f;
        const float b0  = oybF;
        const float b1  = oybF + 1.0f;
        const float b2  = oybF + 2.0f;
        const float b3  = oybF + 3.0f;
        const float b4  = oybF + 4.0f;

        float c0 = 0.f, c1 = 0.f, c2 = 0.f, c3 = 0.f;
        float x0 = 0.f, x1 = 0.f, x2a = 0.f, x3 = 0.f;
        float y0 = 0.f, y1 = 0.f, y2a = 0.f, y3 = 0.f;

        for (int dy = -C; dy <= PY - 1 + C; ++dy) {      // 10 rows, ROLLED
            const int   base = (oy0 + dy + C) * RW + ox; // + (dx+C)
            const float gyF  = oybF + (float)dy;         // exact source row
            #pragma unroll
            for (int dx = -C; dx <= C; ++dx) {           // 7 cols
                float2 xy = sxy[base + dx + C];
                float  w  = sw [base + dx + C];
                const float X = xy.x, Y = xy.y;
                // Column: floor(X) in {oxa-1, oxa}  <=>  X in [oxa-1, oxa+1)
                bool cx  = (X >= cLo) & (X < cHi);
                bool tm1 = (Y >= bm1);
                bool t0  = (Y >= b0);
                bool t1  = (Y >= b1);
                bool t2  = (Y >= b2);
                bool t3  = (Y >= b3);
                bool t4  = (Y >= b4);
                bool m0 = cx & tm1 & !t1;    // Y in [oyb-1, oyb+1)
                bool m1 = cx & t0  & !t2;    // Y in [oyb+0, oyb+2)
                bool m2 = cx & t1  & !t3;    // Y in [oyb+1, oyb+3)
                bool m3 = cx & t2  & !t4;    // Y in [oyb+2, oyb+4)

                float ax = (oxaF + (float)dx) - X;   // == -(fx + eps)
                float ay = gyF - Y;                  // == -(fy + eps)

                float w0 = m0 ? w : 0.0f;
                float w1 = m1 ? w : 0.0f;
                float w2 = m2 ? w : 0.0f;
                float w3 = m3 ? w : 0.0f;
                c0 += w0;  x0  = fmaf(ax, w0, x0 );  y0  = fmaf(ay, w0, y0 );
                c1 += w1;  x1  = fmaf(ax, w1, x1 );  y1  = fmaf(ay, w1, y1 );
                c2 += w2;  x2a = fmaf(ax, w2, x2a);  y2a = fmaf(ay, w2, y2a);
                c3 += w3;  x3  = fmaf(ax, w3, x3 );  y3  = fmaf(ay, w3, y3 );
            }
        }

        // ---- Flush: add outlier planes, normalize, write. Coalesced (lane=ox).
        float cc[PY] = {c0, c1, c2, c3};
        float vx[PY] = {x0, x1, x2a, x3};
        float vy[PY] = {y0, y1, y2a, y3};
        #pragma unroll
        for (int r = 0; r < PY; ++r) {
            int ga = (oyb + r) * W + oxa;
            float c  = cc[r] + cb[ga];
            float fx = vx[r] + xb[ga];
            float fy = vy[r] + yb[ga];
            bool has = c > 0.0f;
            outx[ga] = has ? fx / c : 0.0f;
            outy[ga] = has ? fy / c : 0.0f;
        }
    }
}

// ---------------------------------------------------------------------------
// Fallback path (Round-2 proven): used only if ws can't hold 3 planes.
// ---------------------------------------------------------------------------
__global__ __launch_bounds__(256) void dfp_scatter(
    const float* __restrict__ flow, const float* __restrict__ depth,
    float* __restrict__ out, float* __restrict__ count)
{
    int t = blockIdx.x * 256 + threadIdx.x;
    if (t >= N) return;
    int b = t / HW;
    int p = t - b * HW;
    int i = p / W;
    int j = p - i * W;
    const int fbase = b * 2 * HW;
    float fx = flow[fbase + p];
    float fy = flow[fbase + HW + p];
    float d  = depth[t];
    float x2 = (float)j + fx;
    float y2 = (float)i + fy;
    if (!(x2 >= 0.0f && x2 <= (float)(W - 1) &&
          y2 >= 0.0f && y2 <= (float)(H - 1))) return;
    int xL = (int)floorf(x2);
    int yT = (int)floorf(y2);
    int xR = min(xL + 1, W - 1);
    int yB = min(yT + 1, H - 1);
    float w = d, gx = -fx * w, gy = -fy * w;
    float* ox = out + fbase;
    float* oy = out + fbase + HW;
    float* cnt = count + b * HW;
    int n00 = yT * W + xL, n01 = yT * W + xR, n10 = yB * W + xL, n11 = yB * W + xR;
    unsafeAtomicAdd(&cnt[n00], w); unsafeAtomicAdd(&ox[n00], gx); unsafeAtomicAdd(&oy[n00], gy);
    unsafeAtomicAdd(&cnt[n01], w); unsafeAtomicAdd(&ox[n01], gx); unsafeAtomicAdd(&oy[n01], gy);
    unsafeAtomicAdd(&cnt[n10], w); unsafeAtomicAdd(&ox[n10], gx); unsafeAtomicAdd(&oy[n10], gy);
    unsafeAtomicAdd(&cnt[n11], w); unsafeAtomicAdd(&ox[n11], gx); unsafeAtomicAdd(&oy[n11], gy);
}

__global__ __launch_bounds__(256) void dfp_normalize(
    float* __restrict__ out, const float* __restrict__ count)
{
    int t = blockIdx.x * 256 + threadIdx.x;
    if (t >= N / 4) return;
    int t4 = t * 4;
    int b  = t4 / HW;
    int p  = t4 - b * HW;
    float4 c = *(const float4*)(count + t4);
    float* ox = out + b * 2 * HW + p;
    float* oy = ox + HW;
    float4 vx = *(const float4*)ox;
    float4 vy = *(const float4*)oy;
    vx.x = (c.x > 0.0f) ? vx.x / c.x : 0.0f;
    vx.y = (c.y > 0.0f) ? vx.y / c.y : 0.0f;
    vx.z = (c.z > 0.0f) ? vx.z / c.z : 0.0f;
    vx.w = (c.w > 0.0f) ? vx.w / c.w : 0.0f;
    vy.x = (c.x > 0.0f) ? vy.x / c.x : 0.0f;
    vy.y = (c.y > 0.0f) ? vy.y / c.y : 0.0f;
    vy.z = (c.z > 0.0f) ? vy.z / c.z : 0.0f;
    vy.w = (c.w > 0.0f) ? vy.w / c.w : 0.0f;
    *(float4*)ox = vx;
    *(float4*)oy = vy;
}

extern "C" void kernel_launch(void* const* d_in, const int* in_sizes, int n_in,
                              void* d_out, int out_size, void* d_ws, size_t ws_size,
                              hipStream_t stream)
{
    const float* flow  = (const float*)d_in[0];
    const float* depth = (const float*)d_in[1];
    float* out = (float*)d_out;

    if (ws_size >= (size_t)3 * N * sizeof(float)) {
        // Fast path: bit-exact absolute-coordinate gather + exact outlier pass.
        float* pcnt = (float*)d_ws;
        float* pox  = pcnt + N;
        float* poy  = pox + N;
        hipMemsetAsync(pcnt, 0, (size_t)3 * N * sizeof(float), stream);
        dfp_outlier<<<(N / 4 + 255) / 256, 256, 0, stream>>>(flow, depth, pcnt, pox, poy);
        dim3 grid(W / TX, H / TY, B);   // 20 x 15 x 8 = 2400 blocks
        dfp_gather<<<grid, 256, 0, stream>>>(flow, depth, pcnt, pox, poy, out);
    } else if (ws_size >= (size_t)N * sizeof(float)) {
        // Fallback: proven Round-2 global-atomic path.
        float* count = (float*)d_ws;
        hipMemsetAsync(out,   0, (size_t)2 * N * sizeof(float), stream);
        hipMemsetAsync(count, 0, (size_t)N * sizeof(float),     stream);
        dfp_scatter  <<<(N + 255) / 256,     256, 0, stream>>>(flow, depth, out, count);
        dfp_normalize<<<(N / 4 + 255) / 256, 256, 0, stream>>>(out, count);
    }
    // else: insufficient workspace — cannot run safely.
}

// Round 5
// 247.418 us; speedup vs baseline: 2.6697x; 1.2561x over previous
//
#include <hip/hip_runtime.h>

// Problem constants: B=8, flow (B,2,H,W), depth (B,1,H,W), fp32.
constexpr int B  = 8;
constexpr int H  = 720;
constexpr int W  = 1280;
constexpr int HW = H * W;           // 921600
constexpr int N  = B * HW;          // 7372800

// Gather geometry. Inlier band: fx,fy in [-3,3). An inlier source can only
// touch outputs within Chebyshev distance 3. Gather blocks own 64x16 output
// tiles and scan tile+halo sources.
//
// BIT-EXACT match test (round-2 lesson): the reference floors x2 = fl(gx+fx)
// computed in fp32. We stage the ABSOLUTE fp32 targets (x2, y2) and test
//   column match: x2 in [oxa-1, oxa+1)   (floor(x2) == oxa-1 or oxa)
//   row r match:  y2 in [oyb+r-1, oyb+r+1)
// against exact integer-valued float boundaries — bit-identical to floor.
// Numerators -fx*w, -fy*w are recovered as (gx - x2)*w, (gy - y2)*w
// (error <= ulp/2 ~6e-5 per splat; threshold 9.4e-2; rounds 3-4 absmax 0.016).
// Clamp-edge cases (x2==W-1 or y2==H-1 exactly) go to the outlier pass.
//
// ROUND-3 LESSON: never fully unroll the dy loop (70-candidate unroll ->
// 236 VGPR -> 11% occupancy -> 539 us). dy stays ROLLED.
// ROUND-4 LESSON: VALU-bound at 61% busy with 39% latency idle at 3 waves/
// SIMD (45.4KB LDS -> 3 blocks/CU). This round: TY=16 single-pass + float4
// staging = 24.6KB -> 4 blocks/CU (VGPR-capped), 1 ds_read_b128/candidate.
constexpr int TX = 64;              // tile cols  (1280/64 = 20)
constexpr int TY = 16;              // tile rows  (720/16  = 45)
constexpr int C  = 3;
constexpr int RW = TX + 2 * C;      // 70 staged cols
constexpr int RH = TY + 2 * C;      // 22 staged rows
constexpr int RN = RW * RH;         // 1540 staged sources (24640 B as float4)
constexpr int PY = 4;               // output rows per thread
// 256 threads = 64 cols x 4 row-groups; ONE pass covers the 16 rows.

// ---------------------------------------------------------------------------
// Outlier pass: valid sources NOT handled by the gather fast path, i.e.
// outside the [-3,3) band OR exact clamp hits (x2==W-1 / y2==H-1). Exact
// global atomics into zeroed ws planes. Vectorized 4 px/thread.
// ---------------------------------------------------------------------------
__global__ __launch_bounds__(256) void dfp_outlier(
    const float* __restrict__ flow, const float* __restrict__ depth,
    float* __restrict__ pcnt, float* __restrict__ pox, float* __restrict__ poy)
{
    int t = blockIdx.x * 256 + threadIdx.x;
    if (t >= N / 4) return;
    int t4 = t * 4;
    int b  = t4 / HW;
    int p  = t4 - b * HW;
    int i  = p / W;
    int j  = p - i * W;                       // multiple of 4 (W%4==0)

    const float* fxp = flow + b * 2 * HW;
    float4 fx4 = *(const float4*)(fxp + p);
    float4 fy4 = *(const float4*)(fxp + HW + p);
    float fxs[4] = {fx4.x, fx4.y, fx4.z, fx4.w};
    float fys[4] = {fy4.x, fy4.y, fy4.z, fy4.w};

    float* cb = pcnt + b * HW;
    float* xb = pox  + b * HW;
    float* yb = poy  + b * HW;

    #pragma unroll
    for (int e = 0; e < 4; ++e) {
        float fx = fxs[e], fy = fys[e];
        float x2 = (float)(j + e) + fx;
        float y2 = (float)i + fy;
        bool valid = (x2 >= 0.0f) && (x2 <= (float)(W - 1)) &&
                     (y2 >= 0.0f) && (y2 <= (float)(H - 1));
        bool band  = (fx >= -3.0f) && (fx < 3.0f) &&
                     (fy >= -3.0f) && (fy < 3.0f);
        // Gather fast path handles: band && x2<W-1 && y2<H-1 (given valid).
        // MUST match dfp_gather's staging predicate exactly.
        bool fast  = band && (x2 < (float)(W - 1)) && (y2 < (float)(H - 1));
        if (valid && !fast) {
            float d  = depth[t4 + e];
            int xL = (int)floorf(x2);
            int yT = (int)floorf(y2);
            int xR = min(xL + 1, W - 1);
            int yB = min(yT + 1, H - 1);
            float w = d, gx = -fx * d, gy = -fy * d;
            int n00 = yT * W + xL, n01 = yT * W + xR;
            int n10 = yB * W + xL, n11 = yB * W + xR;
            unsafeAtomicAdd(&cb[n00], w); unsafeAtomicAdd(&xb[n00], gx); unsafeAtomicAdd(&yb[n00], gy);
            unsafeAtomicAdd(&cb[n01], w); unsafeAtomicAdd(&xb[n01], gx); unsafeAtomicAdd(&yb[n01], gy);
            unsafeAtomicAdd(&cb[n10], w); unsafeAtomicAdd(&xb[n10], gx); unsafeAtomicAdd(&yb[n10], gy);
            unsafeAtomicAdd(&cb[n11], w); unsafeAtomicAdd(&xb[n11], gx); unsafeAtomicAdd(&yb[n11], gy);
        }
    }
}

// ---------------------------------------------------------------------------
// Gather kernel v5: single-pass 64x16 tile, float4 staging (one ds_read_b128
// per candidate), rolled dy. Round-4's proven bit-exact inner body unchanged.
// Stage (x2, y2, w, 0); w=0 for dead sources (x2=y2=0 there so masked-zero
// FMAs can't make NaN).
// ---------------------------------------------------------------------------
__global__ __launch_bounds__(256) void dfp_gather(
    const float* __restrict__ flow, const float* __restrict__ depth,
    const float* __restrict__ pcnt, const float* __restrict__ pox,
    const float* __restrict__ poy, float* __restrict__ out)
{
    __shared__ float4 sq[RN];        // (x2, y2, w, pad)  24640 B

    const int tid = threadIdx.x;
    const int tx0 = blockIdx.x * TX;
    const int ty0 = blockIdx.y * TY;
    const int b   = blockIdx.z;

    const float* fxp = flow + b * 2 * HW;
    const float* fyp = fxp + HW;
    const float* dp  = depth + b * HW;

    // ---- Stage tile + halo. w=0 encodes "no contribution here".
    for (int k = tid; k < RN; k += 256) {
        int ry = k / RW;                 // const divisor -> magic mul
        int rx = k - ry * RW;
        int gy = ty0 - C + ry;
        int gx = tx0 - C + rx;
        float X = 0.f, Y = 0.f, w = 0.f;
        if ((unsigned)gy < (unsigned)H && (unsigned)gx < (unsigned)W) {
            int g = gy * W + gx;
            float fx = fxp[g];
            float fy = fyp[g];
            float x2 = (float)gx + fx;   // EXACTLY the reference's fp32 x2
            float y2 = (float)gy + fy;
            // band && valid && not-clamp-edge.
            // MUST match dfp_outlier's complement exactly.
            if (fx >= -3.0f && fx < 3.0f && fy >= -3.0f && fy < 3.0f &&
                x2 >= 0.0f && x2 < (float)(W - 1) &&
                y2 >= 0.0f && y2 < (float)(H - 1)) {
                X = x2; Y = y2; w = dp[g];
            }
        }
        sq[k] = make_float4(X, Y, w, 0.f);
    }
    __syncthreads();

    const int ox  = tid & 63;            // tile-local column (0..63)
    const int g0  = tid >> 6;            // row group (0..3)
    const int oxa = tx0 + ox;            // absolute output column

    const float oxaF = (float)oxa;
    const float cLo  = oxaF - 1.0f;      // exact integers as floats
    const float cHi  = oxaF + 1.0f;

    const int oy0 = g0 * PY;             // tile-local first owned row
    const int oyb = ty0 + oy0;           // absolute row of r=0
    const float oybF = (float)oyb;
    // Row boundaries (exact integer floats): t_k = (y2 >= oyb+k).
    const float bm1 = oybF - 1.0f;
    const float b0  = oybF;
    const float b1  = oybF + 1.0f;
    const float b2  = oybF + 2.0f;
    const float b3  = oybF + 3.0f;
    const float b4  = oybF + 4.0f;

    float c0 = 0.f, c1 = 0.f, c2 = 0.f, c3 = 0.f;
    float x0 = 0.f, x1 = 0.f, x2a = 0.f, x3 = 0.f;
    float y0 = 0.f, y1 = 0.f, y2a = 0.f, y3 = 0.f;

    for (int dy = -C; dy <= PY - 1 + C; ++dy) {      // 10 rows, ROLLED
        const int   base = (oy0 + dy + C) * RW + ox; // + (dx+C)
        const float gyF  = oybF + (float)dy;         // exact source row
        #pragma unroll
        for (int dx = -C; dx <= C; ++dx) {           // 7 cols
            float4 f = sq[base + dx + C];
            const float X = f.x, Y = f.y, w = f.z;
            // Column: floor(X) in {oxa-1, oxa}  <=>  X in [oxa-1, oxa+1)
            bool cx  = (X >= cLo) & (X < cHi);
            bool tm1 = (Y >= bm1);
            bool t0  = (Y >= b0);
            bool t1  = (Y >= b1);
            bool t2  = (Y >= b2);
            bool t3  = (Y >= b3);
            bool t4  = (Y >= b4);
            bool m0 = cx & tm1 & !t1;    // Y in [oyb-1, oyb+1)
            bool m1 = cx & t0  & !t2;    // Y in [oyb+0, oyb+2)
            bool m2 = cx & t1  & !t3;    // Y in [oyb+1, oyb+3)
            bool m3 = cx & t2  & !t4;    // Y in [oyb+2, oyb+4)

            float ax = (oxaF + (float)dx) - X;   // == -(fx + eps)
            float ay = gyF - Y;                  // == -(fy + eps)

            float w0 = m0 ? w : 0.0f;
            float w1 = m1 ? w : 0.0f;
            float w2 = m2 ? w : 0.0f;
            float w3 = m3 ? w : 0.0f;
            c0 += w0;  x0  = fmaf(ax, w0, x0 );  y0  = fmaf(ay, w0, y0 );
            c1 += w1;  x1  = fmaf(ax, w1, x1 );  y1  = fmaf(ay, w1, y1 );
            c2 += w2;  x2a = fmaf(ax, w2, x2a);  y2a = fmaf(ay, w2, y2a);
            c3 += w3;  x3  = fmaf(ax, w3, x3 );  y3  = fmaf(ay, w3, y3 );
        }
    }

    // ---- Flush: add outlier planes, normalize, write. Coalesced (lane=ox).
    float* outx = out + b * 2 * HW;
    float* outy = outx + HW;
    const float* cb = pcnt + b * HW;
    const float* xb = pox  + b * HW;
    const float* yb = poy  + b * HW;

    float cc[PY] = {c0, c1, c2, c3};
    float vx[PY] = {x0, x1, x2a, x3};
    float vy[PY] = {y0, y1, y2a, y3};
    #pragma unroll
    for (int r = 0; r < PY; ++r) {
        int ga = (oyb + r) * W + oxa;
        float c  = cc[r] + cb[ga];
        float fx = vx[r] + xb[ga];
        float fy = vy[r] + yb[ga];
        bool has = c > 0.0f;
        outx[ga] = has ? fx / c : 0.0f;
        outy[ga] = has ? fy / c : 0.0f;
    }
}

// ---------------------------------------------------------------------------
// Fallback path (Round-2 proven): used only if ws can't hold 3 planes.
// ---------------------------------------------------------------------------
__global__ __launch_bounds__(256) void dfp_scatter(
    const float* __restrict__ flow, const float* __restrict__ depth,
    float* __restrict__ out, float* __restrict__ count)
{
    int t = blockIdx.x * 256 + threadIdx.x;
    if (t >= N) return;
    int b = t / HW;
    int p = t - b * HW;
    int i = p / W;
    int j = p - i * W;
    const int fbase = b * 2 * HW;
    float fx = flow[fbase + p];
    float fy = flow[fbase + HW + p];
    float d  = depth[t];
    float x2 = (float)j + fx;
    float y2 = (float)i + fy;
    if (!(x2 >= 0.0f && x2 <= (float)(W - 1) &&
          y2 >= 0.0f && y2 <= (float)(H - 1))) return;
    int xL = (int)floorf(x2);
    int yT = (int)floorf(y2);
    int xR = min(xL + 1, W - 1);
    int yB = min(yT + 1, H - 1);
    float w = d, gx = -fx * w, gy = -fy * w;
    float* ox = out + fbase;
    float* oy = out + fbase + HW;
    float* cnt = count + b * HW;
    int n00 = yT * W + xL, n01 = yT * W + xR, n10 = yB * W + xL, n11 = yB * W + xR;
    unsafeAtomicAdd(&cnt[n00], w); unsafeAtomicAdd(&ox[n00], gx); unsafeAtomicAdd(&oy[n00], gy);
    unsafeAtomicAdd(&cnt[n01], w); unsafeAtomicAdd(&ox[n01], gx); unsafeAtomicAdd(&oy[n01], gy);
    unsafeAtomicAdd(&cnt[n10], w); unsafeAtomicAdd(&ox[n10], gx); unsafeAtomicAdd(&oy[n10], gy);
    unsafeAtomicAdd(&cnt[n11], w); unsafeAtomicAdd(&ox[n11], gx); unsafeAtomicAdd(&oy[n11], gy);
}

__global__ __launch_bounds__(256) void dfp_normalize(
    float* __restrict__ out, const float* __restrict__ count)
{
    int t = blockIdx.x * 256 + threadIdx.x;
    if (t >= N / 4) return;
    int t4 = t * 4;
    int b  = t4 / HW;
    int p  = t4 - b * HW;
    float4 c = *(const float4*)(count + t4);
    float* ox = out + b * 2 * HW + p;
    float* oy = ox + HW;
    float4 vx = *(const float4*)ox;
    float4 vy = *(const float4*)oy;
    vx.x = (c.x > 0.0f) ? vx.x / c.x : 0.0f;
    vx.y = (c.y > 0.0f) ? vx.y / c.y : 0.0f;
    vx.z = (c.z > 0.0f) ? vx.z / c.z : 0.0f;
    vx.w = (c.w > 0.0f) ? vx.w / c.w : 0.0f;
    vy.x = (c.x > 0.0f) ? vy.x / c.x : 0.0f;
    vy.y = (c.y > 0.0f) ? vy.y / c.y : 0.0f;
    vy.z = (c.z > 0.0f) ? vy.z / c.z : 0.0f;
    vy.w = (c.w > 0.0f) ? vy.w / c.w : 0.0f;
    *(float4*)ox = vx;
    *(float4*)oy = vy;
}

extern "C" void kernel_launch(void* const* d_in, const int* in_sizes, int n_in,
                              void* d_out, int out_size, void* d_ws, size_t ws_size,
                              hipStream_t stream)
{
    const float* flow  = (const float*)d_in[0];
    const float* depth = (const float*)d_in[1];
    float* out = (float*)d_out;

    if (ws_size >= (size_t)3 * N * sizeof(float)) {
        // Fast path: bit-exact absolute-coordinate gather + exact outlier pass.
        float* pcnt = (float*)d_ws;
        float* pox  = pcnt + N;
        float* poy  = pox + N;
        hipMemsetAsync(pcnt, 0, (size_t)3 * N * sizeof(float), stream);
        dfp_outlier<<<(N / 4 + 255) / 256, 256, 0, stream>>>(flow, depth, pcnt, pox, poy);
        dim3 grid(W / TX, H / TY, B);   // 20 x 45 x 8 = 7200 blocks
        dfp_gather<<<grid, 256, 0, stream>>>(flow, depth, pcnt, pox, poy, out);
    } else if (ws_size >= (size_t)N * sizeof(float)) {
        // Fallback: proven Round-2 global-atomic path.
        float* count = (float*)d_ws;
        hipMemsetAsync(out,   0, (size_t)2 * N * sizeof(float), stream);
        hipMemsetAsync(count, 0, (size_t)N * sizeof(float),     stream);
        dfp_scatter  <<<(N + 255) / 256,     256, 0, stream>>>(flow, depth, out, count);
        dfp_normalize<<<(N / 4 + 255) / 256, 256, 0, stream>>>(out, count);
    }
    // else: insufficient workspace — cannot run safely.
}